// Round 1
// baseline (298.874 us; speedup 1.0000x reference)
//
#include <hip/hip_runtime.h>

// Affine_Linear_X_YZ: Y = (Bm@A) @ a_term + (Bm@C) @ c_term, fused per point.
// prep_kernel: M = Bm@A, M2 = Bm@C stored interleaved [e][f][2] in d_ws.
// main_kernel: per wave: phase1 lane=d computes a/c terms -> LDS;
//              phase2 lane=f contracts over e with M-pairs from LDS.

#define PPW 16   // points per wave
#define WAVES 4  // waves per block

__global__ __launch_bounds__(256) void prep_kernel(const float* __restrict__ A,
                                                   const float* __restrict__ Bm,
                                                   const float* __restrict__ C,
                                                   float* __restrict__ ws) {
    int tid = blockIdx.x * 256 + threadIdx.x;   // 0..4095
    int f = tid & 63;
    int e = tid >> 6;
    float m = 0.f, m2 = 0.f;
    #pragma unroll 8
    for (int k = 0; k < 64; ++k) {
        float b = Bm[f * 64 + k];
        m  = fmaf(b, A[k * 64 + e], m);
        m2 = fmaf(b, C[k * 64 + e], m2);
    }
    // interleaved layout: ws_float2[e*64 + f] = (M[f,e], M2[f,e]) == index tid
    ((float2*)ws)[tid] = make_float2(m, m2);
}

__global__ __launch_bounds__(256, 4) void main_kernel(const float* __restrict__ X,
                                                      const float* __restrict__ J,
                                                      const float* __restrict__ ws,
                                                      float* __restrict__ out) {
    __shared__ __align__(16) float mm[64 * 128];        // [e][f][2] = 32 KB
    __shared__ __align__(16) float abuf[WAVES][64 * 8]; // per-wave a/c staging, 8 KB

    // cooperative load of M/M2 (8192 floats = 2048 float4)
    {
        const float4* src = (const float4*)ws;
        float4* dst = (float4*)mm;
        #pragma unroll
        for (int i = 0; i < 8; ++i)
            dst[threadIdx.x + 256 * i] = src[threadIdx.x + 256 * i];
    }
    __syncthreads();

    const int wave = threadIdx.x >> 6;
    const int lane = threadIdx.x & 63;
    const int pbase = blockIdx.x * (WAVES * PPW) + wave * PPW;

    const float2* mmp = (const float2*)&mm[lane * 2];   // + e*64 float2 = e*512 B
    const float4* ap4 = (const float4*)&abuf[wave][0];
    const float2* ap2 = (const float2*)&abuf[wave][0];

    #pragma unroll 1
    for (int pi = 0; pi < PPW; ++pi) {
        const int p = pbase + pi;

        // ---- phase 1: lane = d ----
        const float2* jp = (const float2*)(J + (size_t)p * 384 + lane * 6);
        float2 ja = jp[0], jb = jp[1], jc = jp[2];
        const float* xp = X + (size_t)p * 192 + lane * 3;
        float xx = xp[0], xy = xp[1], xz = xp[2];

        // J[..., i, j]: ja=(row0 col0, row0 col1), jb=row1, jc=row2
        float a0x = ja.x, a0y = jb.x, a0z = jc.x;   // col 0
        float a1x = ja.y, a1y = jb.y, a1z = jc.y;   // col 1

        float n0 = sqrtf(a0x * a0x + a0y * a0y + a0z * a0z);
        float r0 = 1.0f / fmaxf(n0, 1e-12f);
        float b1x = a0x * r0, b1y = a0y * r0, b1z = a0z * r0;

        float d  = b1x * a1x + b1y * a1y + b1z * a1z;
        float ux = a1x - d * b1x, uy = a1y - d * b1y, uz = a1z - d * b1z;
        float n2 = sqrtf(ux * ux + uy * uy + uz * uz);
        float r2 = 1.0f / fmaxf(n2, 1e-12f);
        float b2x = ux * r2, b2y = uy * r2, b2z = uz * r2;

        float b3x = b1y * b2z - b1z * b2y;
        float b3y = b1z * b2x - b1x * b2z;
        float b3z = b1x * b2y - b1y * b2x;

        float rt0 = b1x * xx + b1y * xy + b1z * xz;
        float rt1 = b2x * xx + b2y * xy + b2z * xz;
        float rt2 = b3x * xx + b3y * xy + b3z * xz;

        float s = rt1 - rt2, t = rt1 + rt2;
        float av0 = b2x * s + b3x * t;
        float av1 = b2y * s + b3y * t;
        float av2 = b2z * s + b3z * t;
        float cv0 = b1x * rt0, cv1 = b1y * rt0, cv2 = b1z * rt0;

        float* wb = &abuf[wave][lane * 8];
        *((float4*)wb) = make_float4(av0, av1, av2, cv0);
        *((float2*)(wb + 4)) = make_float2(cv1, cv2);

        __syncthreads();

        // ---- phase 2: lane = f ----
        float y0 = 0.f, y1 = 0.f, y2 = 0.f;
        #pragma unroll
        for (int e = 0; e < 64; ++e) {
            float2 mp = mmp[e * 64];        // (M[f,e], M2[f,e]) lane-strided b64
            float4 aa = ap4[e * 2];         // (a0,a1,a2,c0) broadcast b128
            float2 cc = ap2[e * 4 + 2];     // (c1,c2)       broadcast b64
            y0 = fmaf(mp.x, aa.x, fmaf(mp.y, aa.w, y0));
            y1 = fmaf(mp.x, aa.y, fmaf(mp.y, cc.x, y1));
            y2 = fmaf(mp.x, aa.z, fmaf(mp.y, cc.y, y2));
        }

        float* op = out + (size_t)p * 192 + lane * 3;
        op[0] = y0; op[1] = y1; op[2] = y2;

        __syncthreads();   // protect abuf before next point overwrites it
    }
}

extern "C" void kernel_launch(void* const* d_in, const int* in_sizes, int n_in,
                              void* d_out, int out_size, void* d_ws, size_t ws_size,
                              hipStream_t stream) {
    const float* X  = (const float*)d_in[0];
    const float* J  = (const float*)d_in[1];
    const float* A  = (const float*)d_in[2];
    const float* Bm = (const float*)d_in[3];
    const float* C  = (const float*)d_in[4];
    float* out = (float*)d_out;
    float* ws  = (float*)d_ws;

    prep_kernel<<<16, 256, 0, stream>>>(A, Bm, C, ws);

    // 65536 points = 1024 blocks * 4 waves * 16 points
    main_kernel<<<1024, 256, 0, stream>>>(X, J, ws, out);
}

// Round 2
// 212.638 us; speedup vs baseline: 1.4056x; 1.4056x over previous
//
#include <hip/hip_runtime.h>

// Y = (Bm@A) @ a_term + (Bm@C) @ c_term as one bf16 MFMA GEMM:
//   D[f,n] = Acat[f,k] * Z[k,n],  k=0..127 (k<64: M x a_term, k>=64: M2 x c_term)
//   n = point*3 + component, f = 0..63.
// prep_kernel: Acat = [M | M2] in bf16, row-major [64][128] (A-frag friendly).
// main_kernel: per wave (NO __syncthreads anywhere — all LDS is wave-private):
//   phase1: lane=d geometry for 16 points -> Z[n][k] bf16 in LDS (stride 136 = 17*16B,
//           conflict-free b128 B-frag reads)
//   phase2: 48x mfma_f32_16x16x32_bf16, A-frags in registers (loaded once)
//   epilogue: D -> LDS (reuse Z region) -> coalesced float4 global stores

typedef __bf16 bf16x8 __attribute__((ext_vector_type(8)));
typedef float floatx4 __attribute__((ext_vector_type(4)));

#define RS 136  // Z row stride in bf16 (272 B = 17 * 16 B -> conflict-free ds_read_b128)

__global__ __launch_bounds__(256) void prep_kernel(const float* __restrict__ A,
                                                   const float* __restrict__ Bm,
                                                   const float* __restrict__ C,
                                                   __bf16* __restrict__ acat) {
    int tid = blockIdx.x * 256 + threadIdx.x;  // 0..4095
    int f = tid >> 6;
    int e = tid & 63;
    float m = 0.f, m2 = 0.f;
    #pragma unroll 8
    for (int k = 0; k < 64; ++k) {
        float b = Bm[f * 64 + k];
        m  = fmaf(b, A[k * 64 + e], m);
        m2 = fmaf(b, C[k * 64 + e], m2);
    }
    acat[f * 128 + e]      = (__bf16)m;   // M[f][e]
    acat[f * 128 + 64 + e] = (__bf16)m2;  // M2[f][e]
}

__global__ __launch_bounds__(256, 3) void main_kernel(const float* __restrict__ X,
                                                      const float* __restrict__ J,
                                                      const __bf16* __restrict__ acat,
                                                      float* __restrict__ out) {
    // per-wave region: Z = 48 rows x 136 bf16 = 13,056 B; D reuse = 12,288 B
    __shared__ __align__(16) float buf[4][3328];  // 53,248 B total

    const int wave = threadIdx.x >> 6;
    const int lane = threadIdx.x & 63;
    const int l15  = lane & 15;
    const int quad = lane >> 4;
    const int pbase = blockIdx.x * 64 + wave * 16;  // 16 points per wave

    // ---- A-fragments in registers: afrag[mt][kc] holds A[m=mt*16+l15][k=kc*32+quad*8+j]
    bf16x8 afrag[4][4];
    #pragma unroll
    for (int mt = 0; mt < 4; ++mt)
        #pragma unroll
        for (int kc = 0; kc < 4; ++kc)
            afrag[mt][kc] = *(const bf16x8*)(acat + (mt * 16 + l15) * 128 + kc * 32 + quad * 8);

    __bf16* zw = (__bf16*)buf[wave];

    // ---- phase 1: geometry, lane = d, 16 points sequential ----
    #pragma unroll 2
    for (int pi = 0; pi < 16; ++pi) {
        const size_t p = (size_t)(pbase + pi);
        const float2* jp = (const float2*)(J + p * 384) + lane * 3;
        float2 ja = jp[0], jb = jp[1], jc = jp[2];
        const float* xp = X + p * 192 + lane * 3;
        float xx = xp[0], xy = xp[1], xz = xp[2];

        float a0x = ja.x, a0y = jb.x, a0z = jc.x;  // J col 0
        float a1x = ja.y, a1y = jb.y, a1z = jc.y;  // J col 1

        float n0 = sqrtf(a0x * a0x + a0y * a0y + a0z * a0z);
        float r0 = 1.0f / fmaxf(n0, 1e-12f);
        float b1x = a0x * r0, b1y = a0y * r0, b1z = a0z * r0;

        float d  = b1x * a1x + b1y * a1y + b1z * a1z;
        float ux = a1x - d * b1x, uy = a1y - d * b1y, uz = a1z - d * b1z;
        float n2 = sqrtf(ux * ux + uy * uy + uz * uz);
        float r2 = 1.0f / fmaxf(n2, 1e-12f);
        float b2x = ux * r2, b2y = uy * r2, b2z = uz * r2;

        float b3x = b1y * b2z - b1z * b2y;
        float b3y = b1z * b2x - b1x * b2z;
        float b3z = b1x * b2y - b1y * b2x;

        float rt0 = b1x * xx + b1y * xy + b1z * xz;
        float rt1 = b2x * xx + b2y * xy + b2z * xz;
        float rt2 = b3x * xx + b3y * xy + b3z * xz;

        float s = rt1 - rt2, t = rt1 + rt2;

        // Z[n][k]: n = pi*3 + i, k = d (a-part) / 64+d (c-part)
        __bf16* zr = zw + (pi * 3) * RS;
        zr[lane]               = (__bf16)(b2x * s + b3x * t);
        zr[64 + lane]          = (__bf16)(b1x * rt0);
        zr[RS + lane]          = (__bf16)(b2y * s + b3y * t);
        zr[RS + 64 + lane]     = (__bf16)(b1y * rt0);
        zr[2 * RS + lane]      = (__bf16)(b2z * s + b3z * t);
        zr[2 * RS + 64 + lane] = (__bf16)(b1z * rt0);
    }

    __asm__ volatile("s_waitcnt lgkmcnt(0)" ::: "memory");

    // ---- phase 2: 48x mfma 16x16x32 over K=128, 48 n-columns ----
    floatx4 acc[4][3];
    #pragma unroll
    for (int mt = 0; mt < 4; ++mt)
        #pragma unroll
        for (int nt = 0; nt < 3; ++nt)
            acc[mt][nt] = (floatx4){0.f, 0.f, 0.f, 0.f};

    #pragma unroll
    for (int kc = 0; kc < 4; ++kc) {
        #pragma unroll
        for (int nt = 0; nt < 3; ++nt) {
            bf16x8 b = *(const bf16x8*)(zw + (nt * 16 + l15) * RS + kc * 32 + quad * 8);
            #pragma unroll
            for (int mt = 0; mt < 4; ++mt)
                acc[mt][nt] = __builtin_amdgcn_mfma_f32_16x16x32_bf16(
                    afrag[mt][kc], b, acc[mt][nt], 0, 0, 0);
        }
    }

    __asm__ volatile("s_waitcnt lgkmcnt(0)" ::: "memory");

    // ---- epilogue: D[f][n] -> LDS in [p_local][f*3+i] order (reuse Z region) ----
    float* dl = buf[wave];
    #pragma unroll
    for (int mt = 0; mt < 4; ++mt) {
        #pragma unroll
        for (int nt = 0; nt < 3; ++nt) {
            int n  = nt * 16 + l15;
            int pl = (n * 21846) >> 16;  // n / 3 for n < 48
            int i  = n - pl * 3;
            float* dst = dl + pl * 192 + i;
            #pragma unroll
            for (int r = 0; r < 4; ++r) {
                int f = mt * 16 + quad * 4 + r;
                dst[f * 3] = acc[mt][nt][r];
            }
        }
    }

    __asm__ volatile("s_waitcnt lgkmcnt(0)" ::: "memory");

    // coalesced float4 store: 16 points x 192 floats = 768 float4
    const floatx4* s4 = (const floatx4*)dl;
    floatx4* og = (floatx4*)(out + (size_t)pbase * 192);
    #pragma unroll
    for (int t = 0; t < 12; ++t)
        og[t * 64 + lane] = s4[t * 64 + lane];
}

extern "C" void kernel_launch(void* const* d_in, const int* in_sizes, int n_in,
                              void* d_out, int out_size, void* d_ws, size_t ws_size,
                              hipStream_t stream) {
    const float* X  = (const float*)d_in[0];
    const float* J  = (const float*)d_in[1];
    const float* A  = (const float*)d_in[2];
    const float* Bm = (const float*)d_in[3];
    const float* C  = (const float*)d_in[4];
    float* out = (float*)d_out;
    __bf16* acat = (__bf16*)d_ws;  // 64x128 bf16 = 16 KB

    prep_kernel<<<16, 256, 0, stream>>>(A, Bm, C, acat);

    // 65536 points = 1024 blocks x 4 waves x 16 points
    main_kernel<<<1024, 256, 0, stream>>>(X, J, acat, out);
}